// Round 11
// baseline (70.334 us; speedup 1.0000x reference)
//
#include <hip/hip_runtime.h>
#include <math.h>

#define BATCH 8192
#define NLEN 4096
#define THREADS 256
#define PER_THREAD (NLEN / THREADS)  // 16
#define NBIN 64

// d_ws layout
#define OFF_S   (BATCH * 6 * 4)           // feats [8192][6] f32 first (192 KiB)
#define OFF_S2  (OFF_S + 6 * NBIN * 8)    // s_bins  double[6][64]
#define OFF_MX  (OFF_S2 + 6 * NBIN * 8)   // s2_bins double[6][64]
#define BIN_BYTES (6 * NBIN * (8 + 8 + 4))

// ---------------------------------------------------------------------------
// Kernel 1 (round-10 body + binned atomic column stats): ONE BLOCK PER ROW.
// Each thread owns 16 contiguous elements (4x float4, fully coalesced).
// Compaction boundaries via LDS scan-back. f32 per-chunk partials -> f64
// block reduction. Thread 0 writes the row's 6 features AND accumulates
// them into 64-binned per-column sum/sumsq (f64 atomicAdd) + max (u32
// atomicMax; all features are >= 0). Fire-and-forget memory-side RMWs:
// ~128 per address, pipelined, no fences needed (unlike round-8's
// threadfence/release disaster). This deletes k2's latency-bound stats
// walk over 192 KiB of post-boundary feats.
// ---------------------------------------------------------------------------
__global__ __launch_bounds__(THREADS) void hrv_feats_kernel(
    const float* __restrict__ rr, unsigned char* __restrict__ wsb) {
    float* feats = reinterpret_cast<float*>(wsb);
    double* s_bins = reinterpret_cast<double*>(wsb + OFF_S);
    double* s2_bins = reinterpret_cast<double*>(wsb + OFF_S2);
    unsigned int* mx_bins = reinterpret_cast<unsigned int*>(wsb + OFF_MX);

    __shared__ float sh_last[THREADS];
    __shared__ unsigned char sh_has[THREADS];
    __shared__ double sh_sum[4], sh_sumsq[4], sh_sumd2[4];
    __shared__ int sh_cnt[4], sh_nn50[4];

    const int row = blockIdx.x;
    const int t = threadIdx.x;
    const float* r = rr + (size_t)row * NLEN + t * PER_THREAD;

    float x[PER_THREAD];
    float4* xv = reinterpret_cast<float4*>(x);
    const float4* rv = reinterpret_cast<const float4*>(r);
#pragma unroll
    for (int i = 0; i < PER_THREAD / 4; ++i) xv[i] = rv[i];

    float sum = 0.f, sumsq = 0.f, sumd2 = 0.f;
    int cnt = 0, nn50 = 0;
    float first = 0.f, last = 0.f;
    int has = 0;
#pragma unroll
    for (int i = 0; i < PER_THREAD; ++i) {
        float v = x[i];
        if (v > 0.f) {
            sum += v;
            sumsq += v * v;
            ++cnt;
            if (has) {
                float d = v - last;  // same f32 subtraction as reference
                sumd2 += d * d;
                nn50 += (fabsf(d) > 0.05f) ? 1 : 0;
            } else {
                first = v;
                has = 1;
            }
            last = v;
        }
    }
    sh_last[t] = last;
    sh_has[t] = (unsigned char)has;
    __syncthreads();
    // boundary diff: nearest preceding chunk with a valid element
    if (has && t > 0) {
        for (int j = t - 1; j >= 0; --j) {
            if (sh_has[j]) {
                float d = first - sh_last[j];
                sumd2 += d * d;
                nn50 += (fabsf(d) > 0.05f) ? 1 : 0;
                break;
            }
        }
    }

    double dsum = sum, dsumsq = sumsq, dsumd2 = sumd2;
    int icnt = cnt, inn = nn50;
#pragma unroll
    for (int off = 32; off > 0; off >>= 1) {
        dsum += __shfl_down(dsum, off, 64);
        dsumsq += __shfl_down(dsumsq, off, 64);
        dsumd2 += __shfl_down(dsumd2, off, 64);
        icnt += __shfl_down(icnt, off, 64);
        inn += __shfl_down(inn, off, 64);
    }
    const int wave = t >> 6;
    if ((t & 63) == 0) {
        sh_sum[wave] = dsum;
        sh_sumsq[wave] = dsumsq;
        sh_sumd2[wave] = dsumd2;
        sh_cnt[wave] = icnt;
        sh_nn50[wave] = inn;
    }
    __syncthreads();
    if (t == 0) {
        double S = 0, S2 = 0, D2 = 0;
        int C = 0, NN = 0;
        for (int w = 0; w < 4; ++w) {
            S += sh_sum[w];
            S2 += sh_sumsq[w];
            D2 += sh_sumd2[w];
            C += sh_cnt[w];
            NN += sh_nn50[w];
        }
        const float cntf = (float)C;
        const float denom_m = fmaxf(cntf, 1.f);
        const float mean = (float)(S / (double)denom_m);
        const float varsum = (float)(S2 - (double)C * (double)mean * (double)mean);
        const float denom_v = fmaxf(cntf - 1.f, 1.f);
        const float sdnn = sqrtf(fmaxf(varsum / denom_v, 0.f));
        const float rmssd = sqrtf(fmaxf((float)(D2 / (double)denom_v), 0.f));
        const float pnn50 = (float)NN / denom_v;
        const float hr = 60.f / fmaxf(mean, 1e-12f);
        const float cv = sdnn / fmaxf(mean, 1e-12f);
        float f[6] = {mean, sdnn, rmssd, pnn50, hr, cv};
        if (C <= 1) {
#pragma unroll
            for (int c = 0; c < 6; ++c) f[c] = 0.f;
        }
        float* o = feats + row * 6;
        const int bin = row & (NBIN - 1);
#pragma unroll
        for (int c = 0; c < 6; ++c) {
            o[c] = f[c];
            atomicAdd(&s_bins[c * NBIN + bin], (double)f[c]);
            atomicAdd(&s2_bins[c * NBIN + bin], (double)f[c] * (double)f[c]);
            atomicMax(&mx_bins[c * NBIN + bin], __float_as_uint(f[c]));  // f>=0
        }
    }
}

// ---------------------------------------------------------------------------
// Kernel 2 (stats-finalize + MLP): 32 blocks x 256 threads. Wave 0 reads the
// 7.5 KB of bins (one latency round), reduces per column in fixed tree order
// (f64 for the catastrophic (sumsq - B*mean^2) cancellation), writes
// mean/std/max to LDS. Then normalize + 6->16 ReLU -> 32 MLP, one row per
// thread. Deterministic identical stats per block.
// ---------------------------------------------------------------------------
__global__ __launch_bounds__(256) void stats_mlp_kernel(
    const unsigned char* __restrict__ wsb,
    const float* __restrict__ w1, const float* __restrict__ b1,
    const float* __restrict__ w2, const float* __restrict__ b2,
    float* __restrict__ out) {
    const float* feats = reinterpret_cast<const float*>(wsb);
    const double* s_bins = reinterpret_cast<const double*>(wsb + OFF_S);
    const double* s2_bins = reinterpret_cast<const double*>(wsb + OFF_S2);
    const unsigned int* mx_bins =
        reinterpret_cast<const unsigned int*>(wsb + OFF_MX);

    __shared__ float sh_stats[18];  // mean[6], std[6], max[6]
    const int t = threadIdx.x;

    if (t < 64) {
        // issue all 18 loads upfront (lane = bin)
        double S[6], S2[6];
        float M[6];
#pragma unroll
        for (int c = 0; c < 6; ++c) {
            S[c] = s_bins[c * NBIN + t];
            S2[c] = s2_bins[c * NBIN + t];
            M[c] = __uint_as_float(mx_bins[c * NBIN + t]);
        }
#pragma unroll
        for (int off = 32; off; off >>= 1) {
#pragma unroll
            for (int c = 0; c < 6; ++c) {
                S[c] += __shfl_xor(S[c], off, 64);
                S2[c] += __shfl_xor(S2[c], off, 64);
                M[c] = fmaxf(M[c], __shfl_xor(M[c], off, 64));
            }
        }
        if (t < 6) {
            const double meanb = S[t] / (double)BATCH;
            double var =
                (S2[t] - (double)BATCH * meanb * meanb) / (double)(BATCH - 1);
            if (var < 0.0) var = 0.0;
            sh_stats[t] = (float)meanb;
            sh_stats[6 + t] = (float)sqrt(var);
            sh_stats[12 + t] = M[t];
        }
    }
    __syncthreads();

    const int row = blockIdx.x * 256 + t;
    const float* fp = feats + row * 6;
    float f[6];
#pragma unroll
    for (int c = 0; c < 6; ++c) {
        float v = fp[c];
        if (sh_stats[12 + c] > 0.f)
            v = (v - sh_stats[c]) / (sh_stats[6 + c] + 1e-8f);
        f[c] = v;
    }
    float h[16];
#pragma unroll
    for (int j = 0; j < 16; ++j) {
        float a = b1[j];
#pragma unroll
        for (int c = 0; c < 6; ++c) a = fmaf(f[c], w1[c * 16 + j], a);
        h[j] = fmaxf(a, 0.f);
    }
    float o[32];
#pragma unroll
    for (int k = 0; k < 32; ++k) o[k] = b2[k];
#pragma unroll
    for (int j = 0; j < 16; ++j) {
        const float hj = h[j];
#pragma unroll
        for (int k = 0; k < 32; ++k) o[k] = fmaf(hj, w2[j * 32 + k], o[k]);
    }
    float4* ov = reinterpret_cast<float4*>(out + (size_t)row * 32);
    const float4* op = reinterpret_cast<const float4*>(o);
#pragma unroll
    for (int i = 0; i < 8; ++i) ov[i] = op[i];
}

extern "C" void kernel_launch(void* const* d_in, const int* in_sizes, int n_in,
                              void* d_out, int out_size, void* d_ws, size_t ws_size,
                              hipStream_t stream) {
    const float* rr = (const float*)d_in[0];
    const float* w1 = (const float*)d_in[1];
    const float* b1 = (const float*)d_in[2];
    const float* w2 = (const float*)d_in[3];
    const float* b2 = (const float*)d_in[4];
    float* out = (float*)d_out;
    unsigned char* wsb = (unsigned char*)d_ws;

    // zero the 7.5 KB atomic bins (graph-capturable async fill)
    hipMemsetAsync(wsb + OFF_S, 0, BIN_BYTES, stream);
    hrv_feats_kernel<<<BATCH, THREADS, 0, stream>>>(rr, wsb);
    stats_mlp_kernel<<<BATCH / 256, THREADS, 0, stream>>>(wsb, w1, b1, w2, b2, out);
}

// Round 12
// 39.204 us; speedup vs baseline: 1.7940x; 1.7940x over previous
//
#include <hip/hip_runtime.h>
#include <math.h>

#define BATCH 8192
#define NLEN 4096
#define THREADS 256
#define PER_THREAD (NLEN / THREADS)  // 16

// ---------------------------------------------------------------------------
// Kernel 1 (round-10 body, best measured): ONE BLOCK PER ROW, 16 contiguous
// elements per thread (4x float4, fully coalesced). Compaction boundaries
// via LDS scan-back. f32 per-chunk partials -> f64 block reduction.
// NEW: XCD-contiguous block swizzle (8192 = 8 x 1024, bijective) so each
// XCD streams a contiguous 16 MB slab; feats written COLUMN-MAJOR so k2's
// stats walk is float4-coalesced.
// ---------------------------------------------------------------------------
__global__ __launch_bounds__(THREADS) void hrv_feats_kernel(
    const float* __restrict__ rr, float* __restrict__ feats) {
    __shared__ float sh_last[THREADS];
    __shared__ unsigned char sh_has[THREADS];
    __shared__ double sh_sum[4], sh_sumsq[4], sh_sumd2[4];
    __shared__ int sh_cnt[4], sh_nn50[4];

    // XCD-aware swizzle: XCD (bid&7) gets contiguous rows [(bid&7)*1024 ...)
    const int row = ((blockIdx.x & 7) << 10) | (blockIdx.x >> 3);
    const int t = threadIdx.x;
    const float* r = rr + (size_t)row * NLEN + t * PER_THREAD;

    float x[PER_THREAD];
    float4* xv = reinterpret_cast<float4*>(x);
    const float4* rv = reinterpret_cast<const float4*>(r);
#pragma unroll
    for (int i = 0; i < PER_THREAD / 4; ++i) xv[i] = rv[i];

    float sum = 0.f, sumsq = 0.f, sumd2 = 0.f;
    int cnt = 0, nn50 = 0;
    float first = 0.f, last = 0.f;
    int has = 0;
#pragma unroll
    for (int i = 0; i < PER_THREAD; ++i) {
        float v = x[i];
        if (v > 0.f) {
            sum += v;
            sumsq += v * v;
            ++cnt;
            if (has) {
                float d = v - last;  // same f32 subtraction as reference
                sumd2 += d * d;
                nn50 += (fabsf(d) > 0.05f) ? 1 : 0;
            } else {
                first = v;
                has = 1;
            }
            last = v;
        }
    }
    sh_last[t] = last;
    sh_has[t] = (unsigned char)has;
    __syncthreads();
    // boundary diff: nearest preceding chunk with a valid element
    if (has && t > 0) {
        for (int j = t - 1; j >= 0; --j) {
            if (sh_has[j]) {
                float d = first - sh_last[j];
                sumd2 += d * d;
                nn50 += (fabsf(d) > 0.05f) ? 1 : 0;
                break;
            }
        }
    }

    double dsum = sum, dsumsq = sumsq, dsumd2 = sumd2;
    int icnt = cnt, inn = nn50;
#pragma unroll
    for (int off = 32; off > 0; off >>= 1) {
        dsum += __shfl_down(dsum, off, 64);
        dsumsq += __shfl_down(dsumsq, off, 64);
        dsumd2 += __shfl_down(dsumd2, off, 64);
        icnt += __shfl_down(icnt, off, 64);
        inn += __shfl_down(inn, off, 64);
    }
    const int wave = t >> 6;
    if ((t & 63) == 0) {
        sh_sum[wave] = dsum;
        sh_sumsq[wave] = dsumsq;
        sh_sumd2[wave] = dsumd2;
        sh_cnt[wave] = icnt;
        sh_nn50[wave] = inn;
    }
    __syncthreads();
    if (t == 0) {
        double S = 0, S2 = 0, D2 = 0;
        int C = 0, NN = 0;
        for (int w = 0; w < 4; ++w) {
            S += sh_sum[w];
            S2 += sh_sumsq[w];
            D2 += sh_sumd2[w];
            C += sh_cnt[w];
            NN += sh_nn50[w];
        }
        const float cntf = (float)C;
        const float denom_m = fmaxf(cntf, 1.f);
        const float mean = (float)(S / (double)denom_m);
        const float varsum = (float)(S2 - (double)C * (double)mean * (double)mean);
        const float denom_v = fmaxf(cntf - 1.f, 1.f);
        const float sdnn = sqrtf(fmaxf(varsum / denom_v, 0.f));
        const float rmssd = sqrtf(fmaxf((float)(D2 / (double)denom_v), 0.f));
        const float pnn50 = (float)NN / denom_v;
        const float hr = 60.f / fmaxf(mean, 1e-12f);
        const float cv = sdnn / fmaxf(mean, 1e-12f);
        float f[6] = {mean, sdnn, rmssd, pnn50, hr, cv};
        if (C <= 1) {
#pragma unroll
            for (int c = 0; c < 6; ++c) f[c] = 0.f;
        }
#pragma unroll
        for (int c = 0; c < 6; ++c) feats[c * BATCH + row] = f[c];  // col-major
    }
}

// ---------------------------------------------------------------------------
// Kernel 2 (fused col-stats + MLP): 32 blocks x 256 threads.
// Weights staged into LDS FIRST (loads issued before the stats walk, their
// latency overlaps it). Stats: column-major feats read as 3 rounds of 16
// in-flight float4 (vs 8+ serial rounds of scalar loads in round-2's
// row-major walk); f64 accum for the catastrophic (sumsq - B*mean^2)
// cancellation; deterministic identical stats per block. Then normalize +
// 6->16 ReLU -> 32 MLP, one row per thread, weights from LDS.
// ---------------------------------------------------------------------------
__global__ __launch_bounds__(256) void stats_mlp_kernel(
    const float* __restrict__ feats,
    const float* __restrict__ w1, const float* __restrict__ b1,
    const float* __restrict__ w2, const float* __restrict__ b2,
    float* __restrict__ out) {
    __shared__ float sh_w[656];  // w1(96) b1(16) w2(512) b2(32)
    __shared__ double sh_s[4][6], sh_s2[4][6];
    __shared__ float sh_m[4][6];
    __shared__ float sh_stats[18];  // mean[6], std[6], max[6]

    const int t = threadIdx.x;

    // stage weights into LDS (issued first; latency hides under stats walk)
    for (int i = t; i < 656; i += 256) {
        float v;
        if (i < 96) v = w1[i];
        else if (i < 112) v = b1[i - 96];
        else if (i < 624) v = w2[i - 112];
        else v = b2[i - 624];
        sh_w[i] = v;
    }

    // ---- stats: 3 rounds x 16 in-flight float4 over col-major feats ----
    double s[6], s2[6];
    float mx[6];
#pragma unroll
    for (int c = 0; c < 6; ++c) { s[c] = 0.0; s2[c] = 0.0; mx[c] = -INFINITY; }

#pragma unroll
    for (int cp = 0; cp < 3; ++cp) {
        const float4* c0 =
            reinterpret_cast<const float4*>(feats + (2 * cp) * BATCH);
        const float4* c1 =
            reinterpret_cast<const float4*>(feats + (2 * cp + 1) * BATCH);
        float4 buf[16];
#pragma unroll
        for (int k = 0; k < 8; ++k) buf[k] = c0[t + k * 256];
#pragma unroll
        for (int k = 0; k < 8; ++k) buf[8 + k] = c1[t + k * 256];
#pragma unroll
        for (int k = 0; k < 16; ++k) {
            const int c = 2 * cp + (k >> 3);
            const float f[4] = {buf[k].x, buf[k].y, buf[k].z, buf[k].w};
#pragma unroll
            for (int e = 0; e < 4; ++e) {
                s[c] += (double)f[e];
                s2[c] += (double)f[e] * (double)f[e];
                mx[c] = fmaxf(mx[c], f[e]);
            }
        }
    }
#pragma unroll
    for (int off = 32; off; off >>= 1) {
#pragma unroll
        for (int c = 0; c < 6; ++c) {
            s[c] += __shfl_down(s[c], off, 64);
            s2[c] += __shfl_down(s2[c], off, 64);
            mx[c] = fmaxf(mx[c], __shfl_down(mx[c], off, 64));
        }
    }
    if ((t & 63) == 0) {
        const int w = t >> 6;
#pragma unroll
        for (int c = 0; c < 6; ++c) {
            sh_s[w][c] = s[c];
            sh_s2[w][c] = s2[c];
            sh_m[w][c] = mx[c];
        }
    }
    __syncthreads();
    if (t < 6) {
        double S = 0, S2 = 0;
        float M = -INFINITY;
        for (int w = 0; w < 4; ++w) {
            S += sh_s[w][t];
            S2 += sh_s2[w][t];
            M = fmaxf(M, sh_m[w][t]);
        }
        const double meanb = S / (double)BATCH;
        double var = (S2 - (double)BATCH * meanb * meanb) / (double)(BATCH - 1);
        if (var < 0.0) var = 0.0;
        sh_stats[t] = (float)meanb;
        sh_stats[6 + t] = (float)sqrt(var);
        sh_stats[12 + t] = M;
    }
    __syncthreads();

    // ---- MLP: one row per thread, weights from LDS ----
    const int row = blockIdx.x * 256 + t;
    float f[6];
#pragma unroll
    for (int c = 0; c < 6; ++c) {
        float v = feats[c * BATCH + row];  // coalesced across threads
        if (sh_stats[12 + c] > 0.f)
            v = (v - sh_stats[c]) / (sh_stats[6 + c] + 1e-8f);
        f[c] = v;
    }
    float h[16];
#pragma unroll
    for (int j = 0; j < 16; ++j) {
        float a = sh_w[96 + j];
#pragma unroll
        for (int c = 0; c < 6; ++c) a = fmaf(f[c], sh_w[c * 16 + j], a);
        h[j] = fmaxf(a, 0.f);
    }
    float o[32];
#pragma unroll
    for (int k = 0; k < 32; ++k) o[k] = sh_w[624 + k];
#pragma unroll
    for (int j = 0; j < 16; ++j) {
        const float hj = h[j];
#pragma unroll
        for (int k = 0; k < 32; ++k) o[k] = fmaf(hj, sh_w[112 + j * 32 + k], o[k]);
    }
    float4* ov = reinterpret_cast<float4*>(out + (size_t)row * 32);
    const float4* op = reinterpret_cast<const float4*>(o);
#pragma unroll
    for (int i = 0; i < 8; ++i) ov[i] = op[i];
}

extern "C" void kernel_launch(void* const* d_in, const int* in_sizes, int n_in,
                              void* d_out, int out_size, void* d_ws, size_t ws_size,
                              hipStream_t stream) {
    const float* rr = (const float*)d_in[0];
    const float* w1 = (const float*)d_in[1];
    const float* b1 = (const float*)d_in[2];
    const float* w2 = (const float*)d_in[3];
    const float* b2 = (const float*)d_in[4];
    float* out = (float*)d_out;
    float* feats = (float*)d_ws;  // column-major [6][BATCH] = 192 KiB

    hrv_feats_kernel<<<BATCH, THREADS, 0, stream>>>(rr, feats);
    stats_mlp_kernel<<<BATCH / 256, THREADS, 0, stream>>>(feats, w1, b1, w2, b2, out);
}